// Round 11
// baseline (365.367 us; speedup 1.0000x reference)
//
#include <hip/hip_runtime.h>
#include <hip/hip_bf16.h>

typedef __attribute__((ext_vector_type(8))) __bf16 bf16x8;
typedef __attribute__((ext_vector_type(8))) short short8;
typedef __attribute__((ext_vector_type(4))) float f32x4;
typedef __attribute__((ext_vector_type(4))) unsigned int uint4v;
typedef __attribute__((ext_vector_type(2))) unsigned int uint2v;

#define KS 72
#define LOG2E 1.44269504088896340736f

// pack two fp32 -> two bf16 (lo in low short), round-half-up
__device__ __forceinline__ unsigned pack2bf(float lo, float hi) {
    unsigned a = __builtin_bit_cast(unsigned, lo) + 0x8000u;
    unsigned b = __builtin_bit_cast(unsigned, hi) + 0x8000u;
    return __builtin_amdgcn_perm(b, a, 0x07060302u);
}

__device__ __forceinline__ bf16x8 ldfrag(const short* p) {
    short8 s = *reinterpret_cast<const short8*>(p);
    return __builtin_bit_cast(bf16x8, s);
}

// S^T formulation: QK MFMA computes S^T[key][q] (A=K, B=Q); PV computes
// O^T[d][q] (A=V^T, B=P^T). Lane owns one q row (q = lane&15).
// R11 = R10 (permuted-K staging -> lane-local P^T frag; gated masking;
// CU load-balance remap; 67-68us clean counters) + two chain-shorteners:
//  - defer-max (T13, isolated): skip {16-mul acc rescale, l_s mul, m update}
//    when __ballot(mx > m_s + 8) == 0. P <= 2^8 absorbed by final 1/l_s.
//    First tile: m_s=-INF takes the rescale path (alpha=0), correct.
//  - V-frag hoist: load all 8 PV V-frags into regs BEFORE softmax so their
//    ds-latency drains under the exp/pack VALU phase (compiler left them
//    serially after softmax at VGPR=40). Stale columns on partial tiles are
//    multiplied by P=0 (finite stale bf16) -> safe. VGPR ~72 < 85 cap @(512,6).
__global__ __launch_bounds__(512, 6) void vfa_kernel(
    const float* __restrict__ qv, const float* __restrict__ kv, const float* __restrict__ vv,
    const float* __restrict__ eq, const float* __restrict__ ek, const float* __restrict__ ev,
    const float* __restrict__ scale_p, float* __restrict__ out)
{
    constexpr int H = 16, Dh = 64, ENC = 128, SV = 1536;
    constexpr int SS_CUM[9] = {0,144,272,384,480,560,640,704,768};
    constexpr int SEQL[8] = {1152,1008,864,720,640,560,480,400};
    constexpr int QTN[8]  = {9,8,7,6,5,5,4,4};          // ceil(seqlen/128)
    constexpr int OB[8]   = {2080,4096,3232,5104,0,1120,640,1680};
    constexpr int BB[8]   = {1,5,3,7,0,4,2,6};
    constexpr int ISUM[8] = {512,512,512,512,0,0,0,0};

    __shared__ __align__(16) short smem[4*64*KS];   // 2 x {K[64][KS] | V^T[64][KS]}

    // load-balance remap (bijection on [0,768))
    const int bid = (blockIdx.x % 3) * 256 + (blockIdx.x / 3);
    int ss = 0;
    #pragma unroll
    for (int i = 1; i < 8; ++i) ss += (bid >= SS_CUM[i]) ? 1 : 0;
    const int seqlen   = SEQL[ss];
    const int nqt      = QTN[ss];
    const int b        = BB[ss];
    const int isum     = ISUM[ss];
    const int out_base = OB[ss];
    const int local    = bid - SS_CUM[ss];
    const int head     = local / nqt;
    const int qt       = local - head * nqt;

    const int tid  = threadIdx.x;
    const int wave = tid >> 6;          // 0..7, wave owns q rows qt*128 + wave*16 + l15
    const int lane = tid & 63;
    const int quad = lane >> 4;
    const int l15  = lane & 15;

    const float qmul = scale_p[0] * LOG2E;

    // ---- Q fragments (B-operand layout: n=l15, k=quad*8+j) ----
    const int qrow = qt*128 + wave*16 + l15;   // always < padded Lc (checked per ss)
    const float* qrp;
    if (qrow < ENC) qrp = eq + ((b*ENC + qrow)*H + head)*Dh;
    else            qrp = qv + (((b*SV + isum) + (qrow - ENC))*H + head)*Dh;
    bf16x8 qfrag[2];
    #pragma unroll
    for (int f = 0; f < 2; ++f) {
        const float* p = qrp + f*32 + quad*8;
        f32x4 a = *reinterpret_cast<const f32x4*>(p);
        f32x4 c = *reinterpret_cast<const f32x4*>(p + 4);
        uint4v u;
        u[0] = pack2bf(a[0]*qmul, a[1]*qmul);
        u[1] = pack2bf(a[2]*qmul, a[3]*qmul);
        u[2] = pack2bf(c[0]*qmul, c[1]*qmul);
        u[3] = pack2bf(c[2]*qmul, c[3]*qmul);
        qfrag[f] = __builtin_bit_cast(bf16x8, u);
    }

    f32x4 acc[4];                    // O^T: acc[dt] row d = dt*16+quad*4+reg, col q=l15
    #pragma unroll
    for (int dt = 0; dt < 4; ++dt) acc[dt] = {0.f,0.f,0.f,0.f};
    float m_s = -INFINITY, l_s = 0.f;   // per-lane scalars (q = l15)

    // staging roles: waves 0-3 stage K, waves 4-7 stage V (each thread 16 elems)
    const int t2  = tid & 255;
    const int klk = t2 >> 2;            // K: key row 0..63
    const int kd  = (t2 & 3) * 16;      // K: d base
    const int vk0 = (t2 & 15) * 4;      // V: key base (4 consecutive keys)
    const int vd0 = (t2 >> 4) * 4;      // V: d base (4 consecutive d)
    const bool krole = (tid < 256);
    // permuted K dest row: key bits (ks,q1,q0,s,r1,r0) -> row (ks,s,q1,q0,r1,r0)
    const int klkp = (klk & 0x23) | ((klk & 0x04) << 2) | ((klk & 0x18) >> 1);

    f32x4 ld0, ld1, ld2, ld3;           // prefetch registers (live across compute)

    auto issue_loads = [&](int kt_) {
        if (krole) {
            const int kr = kt_*64 + klk;
            const float* krow;
            if (kr < ENC) krow = ek + ((b*ENC + kr)*H + head)*Dh;
            else          krow = kv + (((b*SV + isum) + (kr - ENC))*H + head)*Dh;
            ld0 = *reinterpret_cast<const f32x4*>(krow + kd);
            ld1 = *reinterpret_cast<const f32x4*>(krow + kd + 4);
            ld2 = *reinterpret_cast<const f32x4*>(krow + kd + 8);
            ld3 = *reinterpret_cast<const f32x4*>(krow + kd + 12);
        } else {
            #pragma unroll
            for (int i = 0; i < 4; ++i) {
                const int kr = kt_*64 + vk0 + i;
                const float* vrow;
                if (kr < ENC) vrow = ev + ((b*ENC + kr)*H + head)*Dh;
                else          vrow = vv + (((b*SV + isum) + (kr - ENC))*H + head)*Dh;
                f32x4 t = *reinterpret_cast<const f32x4*>(vrow + vd0);
                if (i == 0) ld0 = t; else if (i == 1) ld1 = t;
                else if (i == 2) ld2 = t; else ld3 = t;
            }
        }
    };

    auto write_tile = [&](short* kb, short* vb) {
        if (krole) {
            // K bf16 at PERMUTED row klkp, 2x ds_write_b128
            uint4v kp;
            kp[0] = pack2bf(ld0[0], ld0[1]);
            kp[1] = pack2bf(ld0[2], ld0[3]);
            kp[2] = pack2bf(ld1[0], ld1[1]);
            kp[3] = pack2bf(ld1[2], ld1[3]);
            *reinterpret_cast<uint4v*>(&kb[klkp*KS + kd]) = kp;
            kp[0] = pack2bf(ld2[0], ld2[1]);
            kp[1] = pack2bf(ld2[2], ld2[3]);
            kp[2] = pack2bf(ld3[0], ld3[1]);
            kp[3] = pack2bf(ld3[2], ld3[3]);
            *reinterpret_cast<uint4v*>(&kb[klkp*KS + kd + 8]) = kp;
        } else {
            // V^T: register 4x4 transpose, 4x ds_write_b64 (natural key order)
            #pragma unroll
            for (int j = 0; j < 4; ++j) {        // d = vd0 + j
                uint2v w;
                w[0] = pack2bf(ld0[j], ld1[j]);   // keys vk0, vk0+1
                w[1] = pack2bf(ld2[j], ld3[j]);   // keys vk0+2, vk0+3
                *reinterpret_cast<uint2v*>(&vb[(vd0 + j)*KS + vk0]) = w;
            }
        }
    };

    const int nkt = (seqlen + 63) >> 6;

    issue_loads(0);

    for (int kt = 0; kt < nkt; ++kt) {
        short* kb = smem + (kt & 1) * (2*64*KS);
        short* vb = kb + 64*KS;

        write_tile(kb, vb);                 // compiler inserts vmcnt wait on ld*
        if (kt + 1 < nkt) issue_loads(kt + 1);   // prefetch rides under compute

        asm volatile("s_waitcnt lgkmcnt(0)" ::: "memory");  // our ds_writes visible
        __builtin_amdgcn_s_barrier();                        // NO vmcnt drain here
        __builtin_amdgcn_sched_barrier(0);

        const int rem = seqlen - kt*64;     // multiple of 16

        // ---- QK^T -> S^T: lane(quad,q) reg r of sub = key 32*(sub>>1)
        //      + 8*quad + 4*(sub&1) + r (permuted staging) ----
        float s[4][4];
        #pragma unroll
        for (int sub = 0; sub < 4; ++sub) {
            if (32*(sub >> 1) < rem) {                 // wave-uniform
                const short* kr0 = &kb[(sub*16 + l15)*KS + quad*8];
                f32x4 sv = {0.f,0.f,0.f,0.f};
                sv = __builtin_amdgcn_mfma_f32_16x16x32_bf16(ldfrag(kr0),      qfrag[0], sv, 0,0,0);
                sv = __builtin_amdgcn_mfma_f32_16x16x32_bf16(ldfrag(kr0 + 32), qfrag[1], sv, 0,0,0);
                #pragma unroll
                for (int r = 0; r < 4; ++r) s[sub][r] = sv[r];
            } else {
                #pragma unroll
                for (int r = 0; r < 4; ++r) s[sub][r] = -INFINITY;
            }
        }
        if (rem < 64) {   // block-uniform: mask only on the (single) partial tile
            #pragma unroll
            for (int sub = 0; sub < 4; ++sub) {
                // per-quad validity: 4-key block fully valid or fully invalid
                const bool vq = (32*(sub >> 1) + 8*quad + 4*(sub & 1)) < rem;
                #pragma unroll
                for (int r = 0; r < 4; ++r) s[sub][r] = vq ? s[sub][r] : -INFINITY;
            }
        }

        // ---- V-frag hoist: ds-latency drains under the softmax VALU phase ----
        bf16x8 vfr[2][4];
        #pragma unroll
        for (int kstep = 0; kstep < 2; ++kstep)
            #pragma unroll
            for (int dt = 0; dt < 4; ++dt)
                vfr[kstep][dt] = ldfrag(&vb[(dt*16 + l15)*KS + kstep*32 + quad*8]);

        // ---- online softmax (per-lane scalar state; defer-max) ----
        float mx = s[0][0];
        #pragma unroll
        for (int sub = 0; sub < 4; ++sub)
            #pragma unroll
            for (int r = 0; r < 4; ++r) mx = fmaxf(mx, s[sub][r]);
        mx = fmaxf(mx, __shfl_xor(mx, 16, 64));
        mx = fmaxf(mx, __shfl_xor(mx, 32, 64));
        // rescale only when the wave's max grew by > 8 (log2 domain);
        // otherwise P <= 2^8, absorbed exactly at final 1/l_s
        if (__ballot(mx > m_s + 8.f)) {
            const float mn = fmaxf(m_s, mx);
            const float alpha = __builtin_amdgcn_exp2f(m_s - mn);
            m_s = mn;
            #pragma unroll
            for (int dt = 0; dt < 4; ++dt)
                #pragma unroll
                for (int r = 0; r < 4; ++r) acc[dt][r] *= alpha;
            l_s *= alpha;
        }

        float rs = 0.f;
        unsigned pk[4][2];
        #pragma unroll
        for (int sub = 0; sub < 4; ++sub) {
            float p0 = __builtin_amdgcn_exp2f(s[sub][0] - m_s);
            float p1 = __builtin_amdgcn_exp2f(s[sub][1] - m_s);
            float p2 = __builtin_amdgcn_exp2f(s[sub][2] - m_s);
            float p3 = __builtin_amdgcn_exp2f(s[sub][3] - m_s);
            rs += (p0 + p1) + (p2 + p3);
            pk[sub][0] = pack2bf(p0, p1);
            pk[sub][1] = pack2bf(p2, p3);
        }
        rs += __shfl_xor(rs, 16, 64);
        rs += __shfl_xor(rs, 32, 64);
        l_s += rs;

        // ---- PV: O^T += V^T x P^T ; P^T B-frag is LANE-LOCAL ----
        #pragma unroll
        for (int kstep = 0; kstep < 2; ++kstep) {
            if (32*kstep < rem) {                      // wave-uniform
                uint4v pf;
                pf[0] = pk[kstep*2 + 0][0];   // keys 8q+0,1
                pf[1] = pk[kstep*2 + 0][1];   // keys 8q+2,3
                pf[2] = pk[kstep*2 + 1][0];   // keys 8q+4,5
                pf[3] = pk[kstep*2 + 1][1];   // keys 8q+6,7
                bf16x8 pfr = __builtin_bit_cast(bf16x8, pf);
                #pragma unroll
                for (int dt = 0; dt < 4; ++dt)
                    acc[dt] = __builtin_amdgcn_mfma_f32_16x16x32_bf16(vfr[kstep][dt], pfr, acc[dt], 0,0,0);
            }
        }
    }

    // ---- epilogue: normalize, transpose via LDS (two 64-row passes), coalesced f32 store ----
    __syncthreads();                       // all waves done reading K/V buffers
    float* tbuf = reinterpret_cast<float*>(smem);   // [64][68] f32 = 17408 B
    const float inv = 1.0f / l_s;
    const int rowl = tid >> 3;             // 0..63
    const int colb = (tid & 7) * 8;        // 0..56
    #pragma unroll
    for (int p = 0; p < 2; ++p) {
        if (p) __syncthreads();            // previous pass's reads done before overwrite
        if ((wave >> 2) == p) {            // waves 0-3 own rows 0-63; waves 4-7 rows 64-127
            #pragma unroll
            for (int dt = 0; dt < 4; ++dt) {
                f32x4 t = acc[dt] * inv;
                *reinterpret_cast<f32x4*>(&tbuf[((wave & 3)*16 + l15)*68 + dt*16 + quad*4]) = t;
            }
        }
        __syncthreads();
        const int grow = qt*128 + p*64 + rowl;
        if (grow < seqlen) {
            float* orow = out + (size_t)(out_base + grow)*(H*Dh) + head*Dh + colb;
            const float* trow = tbuf + rowl*68 + colb;
            *reinterpret_cast<float4*>(orow)     = *reinterpret_cast<const float4*>(trow);
            *reinterpret_cast<float4*>(orow + 4) = *reinterpret_cast<const float4*>(trow + 4);
        }
    }
}

extern "C" void kernel_launch(void* const* d_in, const int* in_sizes, int n_in,
                              void* d_out, int out_size, void* d_ws, size_t ws_size,
                              hipStream_t stream) {
    const float* q     = (const float*)d_in[0];
    const float* k     = (const float*)d_in[1];
    const float* v     = (const float*)d_in[2];
    const float* eq    = (const float*)d_in[3];
    const float* ek    = (const float*)d_in[4];
    const float* ev    = (const float*)d_in[5];
    const float* scale = (const float*)d_in[11];
    float* out = (float*)d_out;

    vfa_kernel<<<dim3(768), dim3(512), 0, stream>>>(q, k, v, eq, ek, ev, scale, out);
}

// Round 12
// 204.267 us; speedup vs baseline: 1.7887x; 1.7887x over previous
//
#include <hip/hip_runtime.h>
#include <hip/hip_bf16.h>

typedef __attribute__((ext_vector_type(8))) __bf16 bf16x8;
typedef __attribute__((ext_vector_type(8))) short short8;
typedef __attribute__((ext_vector_type(4))) float f32x4;
typedef __attribute__((ext_vector_type(4))) unsigned int uint4v;
typedef __attribute__((ext_vector_type(2))) unsigned int uint2v;

#define KS 72
#define LOG2E 1.44269504088896340736f

// pack two fp32 -> two bf16 (lo in low short), round-half-up
__device__ __forceinline__ unsigned pack2bf(float lo, float hi) {
    unsigned a = __builtin_bit_cast(unsigned, lo) + 0x8000u;
    unsigned b = __builtin_bit_cast(unsigned, hi) + 0x8000u;
    return __builtin_amdgcn_perm(b, a, 0x07060302u);
}

__device__ __forceinline__ bf16x8 ldfrag(const short* p) {
    short8 s = *reinterpret_cast<const short8*>(p);
    return __builtin_bit_cast(bf16x8, s);
}

// S^T formulation: QK MFMA computes S^T[key][q] (A=K, B=Q); PV computes
// O^T[d][q] (A=V^T, B=P^T). Lane owns one q row (q = lane&15).
// R12 = R10 exactly (permuted-K staging -> lane-local P^T frag; gated
// masking; CU load-balance remap; 67.5us, floor counters) + ONE change:
//  - defer-max (T13): skip {16-mul acc rescale, l_s mul, m_s update} when
//    __ballot(mx > m_s + 8) == 0. P <= 2^8 absorbed exactly by final 1/l_s.
//    First tile: m_s=-INF -> ballot fires -> rescale path (alpha=0), correct.
//    Zero added live state (R11's V-frag hoist spilled: 32 VGPRs of frags
//    spanning softmax under the (512,6) ~85-VGPR cap -> 394MB scratch).
__global__ __launch_bounds__(512, 6) void vfa_kernel(
    const float* __restrict__ qv, const float* __restrict__ kv, const float* __restrict__ vv,
    const float* __restrict__ eq, const float* __restrict__ ek, const float* __restrict__ ev,
    const float* __restrict__ scale_p, float* __restrict__ out)
{
    constexpr int H = 16, Dh = 64, ENC = 128, SV = 1536;
    constexpr int SS_CUM[9] = {0,144,272,384,480,560,640,704,768};
    constexpr int SEQL[8] = {1152,1008,864,720,640,560,480,400};
    constexpr int QTN[8]  = {9,8,7,6,5,5,4,4};          // ceil(seqlen/128)
    constexpr int OB[8]   = {2080,4096,3232,5104,0,1120,640,1680};
    constexpr int BB[8]   = {1,5,3,7,0,4,2,6};
    constexpr int ISUM[8] = {512,512,512,512,0,0,0,0};

    __shared__ __align__(16) short smem[4*64*KS];   // 2 x {K[64][KS] | V^T[64][KS]}

    // load-balance remap (bijection on [0,768))
    const int bid = (blockIdx.x % 3) * 256 + (blockIdx.x / 3);
    int ss = 0;
    #pragma unroll
    for (int i = 1; i < 8; ++i) ss += (bid >= SS_CUM[i]) ? 1 : 0;
    const int seqlen   = SEQL[ss];
    const int nqt      = QTN[ss];
    const int b        = BB[ss];
    const int isum     = ISUM[ss];
    const int out_base = OB[ss];
    const int local    = bid - SS_CUM[ss];
    const int head     = local / nqt;
    const int qt       = local - head * nqt;

    const int tid  = threadIdx.x;
    const int wave = tid >> 6;          // 0..7, wave owns q rows qt*128 + wave*16 + l15
    const int lane = tid & 63;
    const int quad = lane >> 4;
    const int l15  = lane & 15;

    const float qmul = scale_p[0] * LOG2E;

    // ---- Q fragments (B-operand layout: n=l15, k=quad*8+j) ----
    const int qrow = qt*128 + wave*16 + l15;   // always < padded Lc (checked per ss)
    const float* qrp;
    if (qrow < ENC) qrp = eq + ((b*ENC + qrow)*H + head)*Dh;
    else            qrp = qv + (((b*SV + isum) + (qrow - ENC))*H + head)*Dh;
    bf16x8 qfrag[2];
    #pragma unroll
    for (int f = 0; f < 2; ++f) {
        const float* p = qrp + f*32 + quad*8;
        f32x4 a = *reinterpret_cast<const f32x4*>(p);
        f32x4 c = *reinterpret_cast<const f32x4*>(p + 4);
        uint4v u;
        u[0] = pack2bf(a[0]*qmul, a[1]*qmul);
        u[1] = pack2bf(a[2]*qmul, a[3]*qmul);
        u[2] = pack2bf(c[0]*qmul, c[1]*qmul);
        u[3] = pack2bf(c[2]*qmul, c[3]*qmul);
        qfrag[f] = __builtin_bit_cast(bf16x8, u);
    }

    f32x4 acc[4];                    // O^T: acc[dt] row d = dt*16+quad*4+reg, col q=l15
    #pragma unroll
    for (int dt = 0; dt < 4; ++dt) acc[dt] = {0.f,0.f,0.f,0.f};
    float m_s = -INFINITY, l_s = 0.f;   // per-lane scalars (q = l15)

    // staging roles: waves 0-3 stage K, waves 4-7 stage V (each thread 16 elems)
    const int t2  = tid & 255;
    const int klk = t2 >> 2;            // K: key row 0..63
    const int kd  = (t2 & 3) * 16;      // K: d base
    const int vk0 = (t2 & 15) * 4;      // V: key base (4 consecutive keys)
    const int vd0 = (t2 >> 4) * 4;      // V: d base (4 consecutive d)
    const bool krole = (tid < 256);
    // permuted K dest row: key bits (ks,q1,q0,s,r1,r0) -> row (ks,s,q1,q0,r1,r0)
    const int klkp = (klk & 0x23) | ((klk & 0x04) << 2) | ((klk & 0x18) >> 1);

    f32x4 ld0, ld1, ld2, ld3;           // prefetch registers (live across compute)

    auto issue_loads = [&](int kt_) {
        if (krole) {
            const int kr = kt_*64 + klk;
            const float* krow;
            if (kr < ENC) krow = ek + ((b*ENC + kr)*H + head)*Dh;
            else          krow = kv + (((b*SV + isum) + (kr - ENC))*H + head)*Dh;
            ld0 = *reinterpret_cast<const f32x4*>(krow + kd);
            ld1 = *reinterpret_cast<const f32x4*>(krow + kd + 4);
            ld2 = *reinterpret_cast<const f32x4*>(krow + kd + 8);
            ld3 = *reinterpret_cast<const f32x4*>(krow + kd + 12);
        } else {
            #pragma unroll
            for (int i = 0; i < 4; ++i) {
                const int kr = kt_*64 + vk0 + i;
                const float* vrow;
                if (kr < ENC) vrow = ev + ((b*ENC + kr)*H + head)*Dh;
                else          vrow = vv + (((b*SV + isum) + (kr - ENC))*H + head)*Dh;
                f32x4 t = *reinterpret_cast<const f32x4*>(vrow + vd0);
                if (i == 0) ld0 = t; else if (i == 1) ld1 = t;
                else if (i == 2) ld2 = t; else ld3 = t;
            }
        }
    };

    auto write_tile = [&](short* kb, short* vb) {
        if (krole) {
            // K bf16 at PERMUTED row klkp, 2x ds_write_b128
            uint4v kp;
            kp[0] = pack2bf(ld0[0], ld0[1]);
            kp[1] = pack2bf(ld0[2], ld0[3]);
            kp[2] = pack2bf(ld1[0], ld1[1]);
            kp[3] = pack2bf(ld1[2], ld1[3]);
            *reinterpret_cast<uint4v*>(&kb[klkp*KS + kd]) = kp;
            kp[0] = pack2bf(ld2[0], ld2[1]);
            kp[1] = pack2bf(ld2[2], ld2[3]);
            kp[2] = pack2bf(ld3[0], ld3[1]);
            kp[3] = pack2bf(ld3[2], ld3[3]);
            *reinterpret_cast<uint4v*>(&kb[klkp*KS + kd + 8]) = kp;
        } else {
            // V^T: register 4x4 transpose, 4x ds_write_b64 (natural key order)
            #pragma unroll
            for (int j = 0; j < 4; ++j) {        // d = vd0 + j
                uint2v w;
                w[0] = pack2bf(ld0[j], ld1[j]);   // keys vk0, vk0+1
                w[1] = pack2bf(ld2[j], ld3[j]);   // keys vk0+2, vk0+3
                *reinterpret_cast<uint2v*>(&vb[(vd0 + j)*KS + vk0]) = w;
            }
        }
    };

    const int nkt = (seqlen + 63) >> 6;

    issue_loads(0);

    for (int kt = 0; kt < nkt; ++kt) {
        short* kb = smem + (kt & 1) * (2*64*KS);
        short* vb = kb + 64*KS;

        write_tile(kb, vb);                 // compiler inserts vmcnt wait on ld*
        if (kt + 1 < nkt) issue_loads(kt + 1);   // prefetch rides under compute

        asm volatile("s_waitcnt lgkmcnt(0)" ::: "memory");  // our ds_writes visible
        __builtin_amdgcn_s_barrier();                        // NO vmcnt drain here
        __builtin_amdgcn_sched_barrier(0);

        const int rem = seqlen - kt*64;     // multiple of 16

        // ---- QK^T -> S^T: lane(quad,q) reg r of sub = key 32*(sub>>1)
        //      + 8*quad + 4*(sub&1) + r (permuted staging) ----
        float s[4][4];
        #pragma unroll
        for (int sub = 0; sub < 4; ++sub) {
            if (32*(sub >> 1) < rem) {                 // wave-uniform
                const short* kr0 = &kb[(sub*16 + l15)*KS + quad*8];
                f32x4 sv = {0.f,0.f,0.f,0.f};
                sv = __builtin_amdgcn_mfma_f32_16x16x32_bf16(ldfrag(kr0),      qfrag[0], sv, 0,0,0);
                sv = __builtin_amdgcn_mfma_f32_16x16x32_bf16(ldfrag(kr0 + 32), qfrag[1], sv, 0,0,0);
                #pragma unroll
                for (int r = 0; r < 4; ++r) s[sub][r] = sv[r];
            } else {
                #pragma unroll
                for (int r = 0; r < 4; ++r) s[sub][r] = -INFINITY;
            }
        }
        if (rem < 64) {   // block-uniform: mask only on the (single) partial tile
            #pragma unroll
            for (int sub = 0; sub < 4; ++sub) {
                // per-quad validity: 4-key block fully valid or fully invalid
                const bool vq = (32*(sub >> 1) + 8*quad + 4*(sub & 1)) < rem;
                #pragma unroll
                for (int r = 0; r < 4; ++r) s[sub][r] = vq ? s[sub][r] : -INFINITY;
            }
        }

        // ---- online softmax (per-lane scalar state; defer-max) ----
        float mx = s[0][0];
        #pragma unroll
        for (int sub = 0; sub < 4; ++sub)
            #pragma unroll
            for (int r = 0; r < 4; ++r) mx = fmaxf(mx, s[sub][r]);
        mx = fmaxf(mx, __shfl_xor(mx, 16, 64));
        mx = fmaxf(mx, __shfl_xor(mx, 32, 64));
        // rescale only when the wave's max grew by > 8 (log2 domain);
        // otherwise P <= 2^8, absorbed exactly at final 1/l_s
        if (__ballot(mx > m_s + 8.f)) {
            const float mn = fmaxf(m_s, mx);
            const float alpha = __builtin_amdgcn_exp2f(m_s - mn);
            m_s = mn;
            #pragma unroll
            for (int dt = 0; dt < 4; ++dt)
                #pragma unroll
                for (int r = 0; r < 4; ++r) acc[dt][r] *= alpha;
            l_s *= alpha;
        }

        float rs = 0.f;
        unsigned pk[4][2];
        #pragma unroll
        for (int sub = 0; sub < 4; ++sub) {
            float p0 = __builtin_amdgcn_exp2f(s[sub][0] - m_s);
            float p1 = __builtin_amdgcn_exp2f(s[sub][1] - m_s);
            float p2 = __builtin_amdgcn_exp2f(s[sub][2] - m_s);
            float p3 = __builtin_amdgcn_exp2f(s[sub][3] - m_s);
            rs += (p0 + p1) + (p2 + p3);
            pk[sub][0] = pack2bf(p0, p1);
            pk[sub][1] = pack2bf(p2, p3);
        }
        rs += __shfl_xor(rs, 16, 64);
        rs += __shfl_xor(rs, 32, 64);
        l_s += rs;

        // ---- PV: O^T += V^T x P^T ; P^T B-frag is LANE-LOCAL ----
        #pragma unroll
        for (int kstep = 0; kstep < 2; ++kstep) {
            if (32*kstep < rem) {                      // wave-uniform
                uint4v pf;
                pf[0] = pk[kstep*2 + 0][0];   // keys 8q+0,1
                pf[1] = pk[kstep*2 + 0][1];   // keys 8q+2,3
                pf[2] = pk[kstep*2 + 1][0];   // keys 8q+4,5
                pf[3] = pk[kstep*2 + 1][1];   // keys 8q+6,7
                bf16x8 pfr = __builtin_bit_cast(bf16x8, pf);
                #pragma unroll
                for (int dt = 0; dt < 4; ++dt) {
                    bf16x8 vfr = ldfrag(&vb[(dt*16 + l15)*KS + kstep*32 + quad*8]);
                    acc[dt] = __builtin_amdgcn_mfma_f32_16x16x32_bf16(vfr, pfr, acc[dt], 0,0,0);
                }
            }
        }
    }

    // ---- epilogue: normalize, transpose via LDS (two 64-row passes), coalesced f32 store ----
    __syncthreads();                       // all waves done reading K/V buffers
    float* tbuf = reinterpret_cast<float*>(smem);   // [64][68] f32 = 17408 B
    const float inv = 1.0f / l_s;
    const int rowl = tid >> 3;             // 0..63
    const int colb = (tid & 7) * 8;        // 0..56
    #pragma unroll
    for (int p = 0; p < 2; ++p) {
        if (p) __syncthreads();            // previous pass's reads done before overwrite
        if ((wave >> 2) == p) {            // waves 0-3 own rows 0-63; waves 4-7 rows 64-127
            #pragma unroll
            for (int dt = 0; dt < 4; ++dt) {
                f32x4 t = acc[dt] * inv;
                *reinterpret_cast<f32x4*>(&tbuf[((wave & 3)*16 + l15)*68 + dt*16 + quad*4]) = t;
            }
        }
        __syncthreads();
        const int grow = qt*128 + p*64 + rowl;
        if (grow < seqlen) {
            float* orow = out + (size_t)(out_base + grow)*(H*Dh) + head*Dh + colb;
            const float* trow = tbuf + rowl*68 + colb;
            *reinterpret_cast<float4*>(orow)     = *reinterpret_cast<const float4*>(trow);
            *reinterpret_cast<float4*>(orow + 4) = *reinterpret_cast<const float4*>(trow + 4);
        }
    }
}

extern "C" void kernel_launch(void* const* d_in, const int* in_sizes, int n_in,
                              void* d_out, int out_size, void* d_ws, size_t ws_size,
                              hipStream_t stream) {
    const float* q     = (const float*)d_in[0];
    const float* k     = (const float*)d_in[1];
    const float* v     = (const float*)d_in[2];
    const float* eq    = (const float*)d_in[3];
    const float* ek    = (const float*)d_in[4];
    const float* ev    = (const float*)d_in[5];
    const float* scale = (const float*)d_in[11];
    float* out = (float*)d_out;

    vfa_kernel<<<dim3(768), dim3(512), 0, stream>>>(q, k, v, eq, ek, ev, scale, out);
}